// Round 1
// 4914.202 us; speedup vs baseline: 4.4395x; 4.4395x over previous
//
#include <hip/hip_runtime.h>

// Problem: B=64, T=1024, D=512, F=512, all fp32.
// out[b,t,:] = h_t = tanh(x_t @ W_ih + bias + h_{t-1} @ W_hh)
//
// K1: x_proj GEMM [65536,512]@[512,512]+bias -> d_out (xp buffer, overwritten
//     in-place by the scan; each slot read exactly once before overwrite).
// K2: persistent scan, 256 blocks x 256 threads, group = 16 blocks (4 batch rows).
//     THIS ROUND: removed per-step agent fences (buffer_inv / buffer_wbl2 storms)
//     and the release fetch_add. h payload stays agent-scope atomic (performed at
//     MALL, immune to cross-XCD L2 staleness). Ordering:
//       producer: h atomic-stores -> s_waitcnt vmcnt(0) (in-wave) -> relaxed
//                 atomic store of per-block monotonic tag.
//       consumer: per-THREAD poll of exactly the producer it stages from
//                 (thread tid stages cols {2tid,2tid+1} -> producer tid>>4),
//                 then coherence-point atomic loads. No cache ops anywhere.
//     Finalize is wave-0-only (2 outputs/lane) so the tag release needs no block
//     barrier: 2 barriers/step (staging, red) instead of 4.
//     Skew <= 1 invariant: tag >= t+1 implies that block staged h_{t-1} (staging
//     precedes finalize in its step t), so hbuf parity overwrite at t+1 is safe.

#define RNN_B 64
#define RNN_T 1024
#define RNN_D 512
#define RNN_F 512

// ---------------------------------------------------------------------------
// Kernel 1: x_proj = X @ W_ih + bias.  M=65536, N=512, K=512.  (unchanged)
// ---------------------------------------------------------------------------
__global__ __launch_bounds__(256) void xproj_gemm(
    const float* __restrict__ A,     // [65536, 512]
    const float* __restrict__ W,     // [512, 512]
    const float* __restrict__ bias,  // [512]
    float* __restrict__ C)           // [65536, 512]
{
    __shared__ float As[16][132];
    __shared__ float Bs[16][132];

    const int tid = threadIdx.x;
    const int bid = blockIdx.x;
    const int mt = bid >> 2;
    const int nt = bid & 3;
    const size_t M0 = (size_t)mt * 128;
    const int N0 = nt * 128;

    const int tm = tid >> 4;
    const int tn = tid & 15;

    const int ar = tid >> 2;
    const int ac = (tid & 3) * 4;
    const int br = tid >> 5;
    const int bc = (tid & 31) * 4;

    float acc[8][8];
    #pragma unroll
    for (int i = 0; i < 8; ++i)
        #pragma unroll
        for (int jx = 0; jx < 8; ++jx) acc[i][jx] = 0.f;

    float bv[8];
    #pragma unroll
    for (int i = 0; i < 8; ++i) bv[i] = bias[N0 + tn * 8 + i];

    for (int k0 = 0; k0 < 512; k0 += 16) {
        float4 a0 = *(const float4*)(A + (M0 + ar) * 512 + k0 + ac);
        float4 a1 = *(const float4*)(A + (M0 + ar + 64) * 512 + k0 + ac);
        float4 b0 = *(const float4*)(W + (size_t)(k0 + br) * 512 + N0 + bc);
        float4 b1 = *(const float4*)(W + (size_t)(k0 + br + 8) * 512 + N0 + bc);
        __syncthreads();
        As[ac + 0][ar] = a0.x; As[ac + 1][ar] = a0.y;
        As[ac + 2][ar] = a0.z; As[ac + 3][ar] = a0.w;
        As[ac + 0][ar + 64] = a1.x; As[ac + 1][ar + 64] = a1.y;
        As[ac + 2][ar + 64] = a1.z; As[ac + 3][ar + 64] = a1.w;
        *(float4*)&Bs[br][bc]     = b0;
        *(float4*)&Bs[br + 8][bc] = b1;
        __syncthreads();
        #pragma unroll
        for (int kk = 0; kk < 16; ++kk) {
            float a[8], bb[8];
            *(float4*)&a[0]  = *(const float4*)&As[kk][tm * 8];
            *(float4*)&a[4]  = *(const float4*)&As[kk][tm * 8 + 4];
            *(float4*)&bb[0] = *(const float4*)&Bs[kk][tn * 8];
            *(float4*)&bb[4] = *(const float4*)&Bs[kk][tn * 8 + 4];
            #pragma unroll
            for (int i = 0; i < 8; ++i)
                #pragma unroll
                for (int jx = 0; jx < 8; ++jx)
                    acc[i][jx] = fmaf(a[i], bb[jx], acc[i][jx]);
        }
    }

    #pragma unroll
    for (int i = 0; i < 8; ++i) {
        float* crow = C + (M0 + tm * 8 + i) * 512 + N0 + tn * 8;
        float4 o0, o1;
        o0.x = acc[i][0] + bv[0]; o0.y = acc[i][1] + bv[1];
        o0.z = acc[i][2] + bv[2]; o0.w = acc[i][3] + bv[3];
        o1.x = acc[i][4] + bv[4]; o1.y = acc[i][5] + bv[5];
        o1.z = acc[i][6] + bv[6]; o1.w = acc[i][7] + bv[7];
        *(float4*)crow = o0;
        *((float4*)crow + 1) = o1;
    }
}

// ---------------------------------------------------------------------------
// Kernel 2: the scan.
// ---------------------------------------------------------------------------
__global__ __launch_bounds__(256, 1) void rnn_scan(
    const float* __restrict__ whh,   // [512, 512]
    float* __restrict__ out,         // [64, 1024, 512]; holds xp, overwritten with h
    float* __restrict__ hbuf,        // [2][64][512] double buffer
    unsigned* __restrict__ tags)     // [16][16][16] u32, 64B-padded, memset 0
{
    __shared__ float hs[4][512];        // h_{t-1} for my 4 rows (8 KB)
    __shared__ float red[8][4][32];     // partial sums [kq][row][col] (4 KB)

    const int tid = threadIdx.x;
    const int b = blockIdx.x;
    const int r = b & 15;            // row group 0..15 -> batch rows 4r..4r+3
    const int s = b >> 4;            // col slice 0..15 -> cols 32s..32s+31
    const int j = tid & 31;
    const int kq = tid >> 5;         // 0..7
    const int kbase = kq * 64;
    const int col = s * 32 + j;
    const int row0 = r * 4;

    // One-time: weight slice into registers. 64 floats/thread.
    float wreg[64];
    #pragma unroll
    for (int kk = 0; kk < 64; ++kk)
        wreg[kk] = whh[(size_t)(kbase + kk) * RNN_F + col];

    // Per-block monotonic tag (64B stride). Thread tid stages hbuf cols
    // {2*tid, 2*tid+1}, produced by block s' = tid>>4 of this group.
    unsigned* mytag = tags + (unsigned)(r * 16 + s) * 16u;
    const unsigned* polltag = tags + (unsigned)(r * 16 + (tid >> 4)) * 16u;

    const int fr0 = (tid >> 5) & 1;  // finalize rows for wave 0: fr0, fr0+2

    #pragma unroll 1
    for (int t = 0; t < RNN_T; ++t) {
        // Prefetch xp for wave 0's two output elements BEFORE the poll.
        // Safe: these (row,col,t) slots are written only by THIS block, step t.
        float xpv0 = 0.f, xpv1 = 0.f;
        if (tid < 64) {
            xpv0 = out[((size_t)(row0 + fr0) * RNN_T + t) * RNN_F + col];
            xpv1 = out[((size_t)(row0 + fr0 + 2) * RNN_T + t) * RNN_F + col];
        }

        if (t > 0) {
            // Per-thread poll of exactly the producer this thread stages from.
            // Relaxed agent atomic load = coherence-point read; no cache ops.
            while (__hip_atomic_load(polltag, __ATOMIC_RELAXED,
                                     __HIP_MEMORY_SCOPE_AGENT) < (unsigned)t)
                __builtin_amdgcn_s_sleep(1);
            // Stage h_{t-1}: 4x 8B coherence-point loads, all from my producer.
            const unsigned long long* src = (const unsigned long long*)(hbuf +
                (size_t)((t + 1) & 1) * (RNN_B * RNN_F) + (size_t)row0 * RNN_F);
            unsigned long long* dst = (unsigned long long*)&hs[0][0];
            #pragma unroll
            for (int i = 0; i < 4; ++i) {
                dst[tid + 256 * i] = __hip_atomic_load(
                    src + tid + 256 * i, __ATOMIC_RELAXED,
                    __HIP_MEMORY_SCOPE_AGENT);
            }
            __syncthreads();
        }

        float acc0 = 0.f, acc1 = 0.f, acc2 = 0.f, acc3 = 0.f;
        if (t > 0) {
            #pragma unroll
            for (int kk = 0; kk < 64; kk += 4) {
                float4 h0 = *(const float4*)&hs[0][kbase + kk];
                float4 h1 = *(const float4*)&hs[1][kbase + kk];
                float4 h2 = *(const float4*)&hs[2][kbase + kk];
                float4 h3 = *(const float4*)&hs[3][kbase + kk];
                acc0 = fmaf(h0.x, wreg[kk+0], acc0);
                acc0 = fmaf(h0.y, wreg[kk+1], acc0);
                acc0 = fmaf(h0.z, wreg[kk+2], acc0);
                acc0 = fmaf(h0.w, wreg[kk+3], acc0);
                acc1 = fmaf(h1.x, wreg[kk+0], acc1);
                acc1 = fmaf(h1.y, wreg[kk+1], acc1);
                acc1 = fmaf(h1.z, wreg[kk+2], acc1);
                acc1 = fmaf(h1.w, wreg[kk+3], acc1);
                acc2 = fmaf(h2.x, wreg[kk+0], acc2);
                acc2 = fmaf(h2.y, wreg[kk+1], acc2);
                acc2 = fmaf(h2.z, wreg[kk+2], acc2);
                acc2 = fmaf(h2.w, wreg[kk+3], acc2);
                acc3 = fmaf(h3.x, wreg[kk+0], acc3);
                acc3 = fmaf(h3.y, wreg[kk+1], acc3);
                acc3 = fmaf(h3.z, wreg[kk+2], acc3);
                acc3 = fmaf(h3.w, wreg[kk+3], acc3);
            }
        }
        red[kq][0][j] = acc0;
        red[kq][1][j] = acc1;
        red[kq][2][j] = acc2;
        red[kq][3][j] = acc3;
        __syncthreads();

        // Finalize: wave 0 only (2 outputs/lane) -> tag release needs only an
        // in-wave vmcnt drain, no block barrier. Waves 1..7 fall through to the
        // next step's prefetch/poll (they block on tags, which require this
        // wave-0 finalize -> no hs/red overwrite race; see header).
        if (tid < 64) {
            float s0 = 0.f, s1 = 0.f;
            #pragma unroll
            for (int q = 0; q < 8; ++q) {
                s0 += red[q][fr0][j];
                s1 += red[q][fr0 + 2][j];
            }
            float v0 = tanhf(xpv0 + s0);
            float v1 = tanhf(xpv1 + s1);
            out[((size_t)(row0 + fr0) * RNN_T + t) * RNN_F + col] = v0;
            out[((size_t)(row0 + fr0 + 2) * RNN_T + t) * RNN_F + col] = v1;
            float* hb = hbuf + (size_t)(t & 1) * (RNN_B * RNN_F);
            __hip_atomic_store(hb + (size_t)(row0 + fr0) * RNN_F + col, v0,
                               __ATOMIC_RELAXED, __HIP_MEMORY_SCOPE_AGENT);
            __hip_atomic_store(hb + (size_t)(row0 + fr0 + 2) * RNN_F + col, v1,
                               __ATOMIC_RELAXED, __HIP_MEMORY_SCOPE_AGENT);
            // Drain this wave's h stores to the coherence point, then publish.
            asm volatile("s_waitcnt vmcnt(0)" ::: "memory");
            if (tid == 0)
                __hip_atomic_store(mytag, (unsigned)(t + 1),
                                   __ATOMIC_RELAXED, __HIP_MEMORY_SCOPE_AGENT);
        }
    }
}

extern "C" void kernel_launch(void* const* d_in, const int* in_sizes, int n_in,
                              void* d_out, int out_size, void* d_ws, size_t ws_size,
                              hipStream_t stream) {
    const float* X    = (const float*)d_in[0];  // [64,1024,512]
    const float* Wih  = (const float*)d_in[1];  // [512,512]
    const float* Whh  = (const float*)d_in[2];  // [512,512]
    const float* bias = (const float*)d_in[3];  // [512]
    float* out = (float*)d_out;                 // [64,1024,512]

    float* hbuf = (float*)d_ws;                 // 2*64*512 fp32 = 256 KB
    unsigned* tags = (unsigned*)((char*)d_ws + 2 * RNN_B * RNN_F * sizeof(float));

    hipMemsetAsync(tags, 0, 16 * 16 * 16 * sizeof(unsigned), stream);

    xproj_gemm<<<dim3(2048), dim3(256), 0, stream>>>(X, Wih, bias, out);
    rnn_scan<<<dim3(256), dim3(256), 0, stream>>>(Whh, out, hbuf, tags);
}

// Round 2
// 4282.005 us; speedup vs baseline: 5.0950x; 1.1476x over previous
//
#include <hip/hip_runtime.h>

// Problem: B=64, T=1024, D=512, F=512, all fp32.
// out[b,t,:] = h_t = tanh(x_t @ W_ih + bias + h_{t-1} @ W_hh)
//
// K1: x_proj GEMM [65536,512]@[512,512]+bias -> d_out (xp buffer, overwritten
//     in-place by the scan; each slot read exactly once before overwrite).
// K2: persistent scan, 256 blocks x 256 threads, group = 16 blocks (4 batch rows).
//     THIS ROUND: fused tag+data. h is exchanged as 8-byte packets
//     {lo32 = float bits, hi32 = step tag} stored/loaded with single relaxed
//     agent-scope 8B atomics (performed at MALL -> coherence-point, atomic ->
//     value+tag seen together, self-validating). This deletes the producer's
//     vmcnt(0) drain, the separate tag store, and the consumer's tag-poll round
//     trip: critical path is ONE store->MALL->poll-load hop. Zero fences needed
//     (no inter-location ordering anywhere).
//     Skew <= 1 invariant (unchanged): packet with tag t (parity t&1) is
//     overwritten at t+2 only after all 16 in-group blocks produced t+1, which
//     requires each consumed tag t. Stale tag in a slot is t-2 or 0xFFFFFFFF
//     (initial memset) -> exact-equality check never false-positives.
//     VGPR < 168 -> all 256 blocks co-resident -> no deadlock on the spin.

#define RNN_B 64
#define RNN_T 1024
#define RNN_D 512
#define RNN_F 512

// ---------------------------------------------------------------------------
// Kernel 1: x_proj = X @ W_ih + bias.  M=65536, N=512, K=512.  (unchanged)
// ---------------------------------------------------------------------------
__global__ __launch_bounds__(256) void xproj_gemm(
    const float* __restrict__ A,     // [65536, 512]
    const float* __restrict__ W,     // [512, 512]
    const float* __restrict__ bias,  // [512]
    float* __restrict__ C)           // [65536, 512]
{
    __shared__ float As[16][132];
    __shared__ float Bs[16][132];

    const int tid = threadIdx.x;
    const int bid = blockIdx.x;
    const int mt = bid >> 2;
    const int nt = bid & 3;
    const size_t M0 = (size_t)mt * 128;
    const int N0 = nt * 128;

    const int tm = tid >> 4;
    const int tn = tid & 15;

    const int ar = tid >> 2;
    const int ac = (tid & 3) * 4;
    const int br = tid >> 5;
    const int bc = (tid & 31) * 4;

    float acc[8][8];
    #pragma unroll
    for (int i = 0; i < 8; ++i)
        #pragma unroll
        for (int jx = 0; jx < 8; ++jx) acc[i][jx] = 0.f;

    float bv[8];
    #pragma unroll
    for (int i = 0; i < 8; ++i) bv[i] = bias[N0 + tn * 8 + i];

    for (int k0 = 0; k0 < 512; k0 += 16) {
        float4 a0 = *(const float4*)(A + (M0 + ar) * 512 + k0 + ac);
        float4 a1 = *(const float4*)(A + (M0 + ar + 64) * 512 + k0 + ac);
        float4 b0 = *(const float4*)(W + (size_t)(k0 + br) * 512 + N0 + bc);
        float4 b1 = *(const float4*)(W + (size_t)(k0 + br + 8) * 512 + N0 + bc);
        __syncthreads();
        As[ac + 0][ar] = a0.x; As[ac + 1][ar] = a0.y;
        As[ac + 2][ar] = a0.z; As[ac + 3][ar] = a0.w;
        As[ac + 0][ar + 64] = a1.x; As[ac + 1][ar + 64] = a1.y;
        As[ac + 2][ar + 64] = a1.z; As[ac + 3][ar + 64] = a1.w;
        *(float4*)&Bs[br][bc]     = b0;
        *(float4*)&Bs[br + 8][bc] = b1;
        __syncthreads();
        #pragma unroll
        for (int kk = 0; kk < 16; ++kk) {
            float a[8], bb[8];
            *(float4*)&a[0]  = *(const float4*)&As[kk][tm * 8];
            *(float4*)&a[4]  = *(const float4*)&As[kk][tm * 8 + 4];
            *(float4*)&bb[0] = *(const float4*)&Bs[kk][tn * 8];
            *(float4*)&bb[4] = *(const float4*)&Bs[kk][tn * 8 + 4];
            #pragma unroll
            for (int i = 0; i < 8; ++i)
                #pragma unroll
                for (int jx = 0; jx < 8; ++jx)
                    acc[i][jx] = fmaf(a[i], bb[jx], acc[i][jx]);
        }
    }

    #pragma unroll
    for (int i = 0; i < 8; ++i) {
        float* crow = C + (M0 + tm * 8 + i) * 512 + N0 + tn * 8;
        float4 o0, o1;
        o0.x = acc[i][0] + bv[0]; o0.y = acc[i][1] + bv[1];
        o0.z = acc[i][2] + bv[2]; o0.w = acc[i][3] + bv[3];
        o1.x = acc[i][4] + bv[4]; o1.y = acc[i][5] + bv[5];
        o1.z = acc[i][6] + bv[6]; o1.w = acc[i][7] + bv[7];
        *(float4*)crow = o0;
        *((float4*)crow + 1) = o1;
    }
}

// ---------------------------------------------------------------------------
// Kernel 2: the scan.
// ---------------------------------------------------------------------------
__global__ __launch_bounds__(256, 1) void rnn_scan(
    const float* __restrict__ whh,          // [512, 512]
    float* __restrict__ out,                // [64,1024,512]; xp, overwritten with h
    unsigned long long* __restrict__ hbuf)  // [2][64][512] 8B {val,tag} packets
{
    __shared__ float hs[4][512];        // h_{t-1} for my 4 rows (8 KB)
    __shared__ float red[8][4][32];     // partial sums [kq][row][col] (4 KB)

    const int tid = threadIdx.x;
    const int b = blockIdx.x;
    const int r = b & 15;            // row group 0..15 -> batch rows 4r..4r+3
    const int s = b >> 4;            // col slice 0..15 -> cols 32s..32s+31
    const int j = tid & 31;
    const int kq = tid >> 5;         // 0..7
    const int kbase = kq * 64;
    const int col = s * 32 + j;
    const int row0 = r * 4;

    // One-time: weight slice into registers. 64 floats/thread.
    float wreg[64];
    #pragma unroll
    for (int kk = 0; kk < 64; ++kk)
        wreg[kk] = whh[(size_t)(kbase + kk) * RNN_F + col];

    const int fr0 = (tid >> 5) & 1;  // finalize rows for wave 0: fr0, fr0+2

    #pragma unroll 1
    for (int t = 0; t < RNN_T; ++t) {
        // Prefetch xp for wave 0's two output elements BEFORE the poll.
        // Safe: these (row,col,t) slots are written only by THIS block, step t.
        float xpv0 = 0.f, xpv1 = 0.f;
        if (tid < 64) {
            xpv0 = out[((size_t)(row0 + fr0) * RNN_T + t) * RNN_F + col];
            xpv1 = out[((size_t)(row0 + fr0 + 2) * RNN_T + t) * RNN_F + col];
        }

        if (t > 0) {
            // Thread tid stages cols {2tid, 2tid+1} of rows row0..row0+3.
            // Poll the 8 self-validating packets directly (no separate tag).
            const unsigned long long* src = hbuf +
                (size_t)((t + 1) & 1) * (RNN_B * RNN_F) +
                (size_t)row0 * RNN_F + 2 * (tid & 255);
            const unsigned tagw = (unsigned)(t - 1);
            unsigned long long e[4][2];
            for (;;) {
                #pragma unroll
                for (int i = 0; i < 4; ++i) {
                    e[i][0] = __hip_atomic_load(src + i * RNN_F + 0,
                        __ATOMIC_RELAXED, __HIP_MEMORY_SCOPE_AGENT);
                    e[i][1] = __hip_atomic_load(src + i * RNN_F + 1,
                        __ATOMIC_RELAXED, __HIP_MEMORY_SCOPE_AGENT);
                }
                bool ok = true;
                #pragma unroll
                for (int i = 0; i < 4; ++i)
                    ok = ok && ((unsigned)(e[i][0] >> 32) == tagw)
                            && ((unsigned)(e[i][1] >> 32) == tagw);
                if (ok) break;
                __builtin_amdgcn_s_sleep(1);
            }
            // hs as ulong[1024]: word w covers hs[w>>8][2*(w&255)] pair.
            unsigned long long* dst = (unsigned long long*)&hs[0][0];
            #pragma unroll
            for (int i = 0; i < 4; ++i)
                dst[i * 256 + tid] =
                    (e[i][0] & 0xFFFFFFFFull) | (e[i][1] << 32);
            __syncthreads();
        }

        float acc0 = 0.f, acc1 = 0.f, acc2 = 0.f, acc3 = 0.f;
        if (t > 0) {
            #pragma unroll
            for (int kk = 0; kk < 64; kk += 4) {
                float4 h0 = *(const float4*)&hs[0][kbase + kk];
                float4 h1 = *(const float4*)&hs[1][kbase + kk];
                float4 h2 = *(const float4*)&hs[2][kbase + kk];
                float4 h3 = *(const float4*)&hs[3][kbase + kk];
                acc0 = fmaf(h0.x, wreg[kk+0], acc0);
                acc0 = fmaf(h0.y, wreg[kk+1], acc0);
                acc0 = fmaf(h0.z, wreg[kk+2], acc0);
                acc0 = fmaf(h0.w, wreg[kk+3], acc0);
                acc1 = fmaf(h1.x, wreg[kk+0], acc1);
                acc1 = fmaf(h1.y, wreg[kk+1], acc1);
                acc1 = fmaf(h1.z, wreg[kk+2], acc1);
                acc1 = fmaf(h1.w, wreg[kk+3], acc1);
                acc2 = fmaf(h2.x, wreg[kk+0], acc2);
                acc2 = fmaf(h2.y, wreg[kk+1], acc2);
                acc2 = fmaf(h2.z, wreg[kk+2], acc2);
                acc2 = fmaf(h2.w, wreg[kk+3], acc2);
                acc3 = fmaf(h3.x, wreg[kk+0], acc3);
                acc3 = fmaf(h3.y, wreg[kk+1], acc3);
                acc3 = fmaf(h3.z, wreg[kk+2], acc3);
                acc3 = fmaf(h3.w, wreg[kk+3], acc3);
            }
        }
        red[kq][0][j] = acc0;
        red[kq][1][j] = acc1;
        red[kq][2][j] = acc2;
        red[kq][3][j] = acc3;
        __syncthreads();

        // Finalize: wave 0 only (2 outputs/lane). Fire-and-forget packet
        // stores -- no drain, no tag, no fence. hbuf stores issued FIRST
        // (they are the cross-block critical path), out stores after.
        if (tid < 64) {
            float s0 = 0.f, s1 = 0.f;
            #pragma unroll
            for (int q = 0; q < 8; ++q) {
                s0 += red[q][fr0][j];
                s1 += red[q][fr0 + 2][j];
            }
            float v0 = tanhf(xpv0 + s0);
            float v1 = tanhf(xpv1 + s1);
            unsigned long long* hb = hbuf + (size_t)(t & 1) * (RNN_B * RNN_F);
            const unsigned long long tg = (unsigned long long)(unsigned)t << 32;
            __hip_atomic_store(hb + (size_t)(row0 + fr0) * RNN_F + col,
                               tg | __float_as_uint(v0),
                               __ATOMIC_RELAXED, __HIP_MEMORY_SCOPE_AGENT);
            __hip_atomic_store(hb + (size_t)(row0 + fr0 + 2) * RNN_F + col,
                               tg | __float_as_uint(v1),
                               __ATOMIC_RELAXED, __HIP_MEMORY_SCOPE_AGENT);
            out[((size_t)(row0 + fr0) * RNN_T + t) * RNN_F + col] = v0;
            out[((size_t)(row0 + fr0 + 2) * RNN_T + t) * RNN_F + col] = v1;
        }
        // Waves 1..7 fall straight through to the next step's prefetch/poll;
        // hs/red overwrite races excluded by the staging barrier requiring
        // wave 0 (i.e. finalize(t) complete) -- see header.
    }
}

extern "C" void kernel_launch(void* const* d_in, const int* in_sizes, int n_in,
                              void* d_out, int out_size, void* d_ws, size_t ws_size,
                              hipStream_t stream) {
    const float* X    = (const float*)d_in[0];  // [64,1024,512]
    const float* Wih  = (const float*)d_in[1];  // [512,512]
    const float* Whh  = (const float*)d_in[2];  // [512,512]
    const float* bias = (const float*)d_in[3];  // [512]
    float* out = (float*)d_out;                 // [64,1024,512]

    unsigned long long* hbuf = (unsigned long long*)d_ws;  // 2*64*512*8B = 512 KB

    // Tag field of every packet -> 0xFFFFFFFF (matches no step).
    hipMemsetAsync(hbuf, 0xFF, (size_t)2 * RNN_B * RNN_F * sizeof(unsigned long long),
                   stream);

    xproj_gemm<<<dim3(2048), dim3(256), 0, stream>>>(X, Wih, bias, out);
    rnn_scan<<<dim3(256), dim3(256), 0, stream>>>(Whh, out, hbuf);
}

// Round 4
// 3980.064 us; speedup vs baseline: 5.4815x; 1.0759x over previous
//
#include <hip/hip_runtime.h>

// Problem: B=64, T=1024, D=512, F=512, all fp32.
// out[b,t,:] = h_t = tanh(x_t @ W_ih + bias + h_{t-1} @ W_hh)
//
// K1: x_proj GEMM [65536,512]@[512,512]+bias -> d_out (xp buffer, overwritten
//     in-place by the scan; each slot read exactly once before overwrite).
// K2: persistent scan, 256 blocks x 256 threads, group = 16 blocks (4 batch rows).
//     Exchange: 8-byte self-validating packets {lo32=float bits, hi32=step tag}
//     via relaxed agent-scope 8B atomics (MALL coherence point, R2-verified).
//     (Resubmission of R3 -- container-level infra failure, no kernel signal.
//      Deadlock audit: wait graph is a DAG over (block,t); all 256 blocks
//      co-resident; barrier-free staging is same-wave by construction.)
//     (a) Barrier-free exchange: lane (kq=tid>>5, j=tid&31) polls+stages the
//         EXACT k-slice its own half-wave FMAs (cols kq*64+2j,+1 x 4 rows =
//         32 lanes x 8 = 256 values). Intra-wave lockstep -> no stage barrier;
//         each wave waits only on its 4 producer blocks, not all 16.
//     (b) xp loads moved AFTER the poll (they were serialized into the poll's
//         vmcnt(0) wait -> 400-900cy of HBM latency on the critical path every
//         step). Now hidden under the FMA phase.
//     (c) red parity-double-buffered (no barrier between stage and FMA means
//         red[t] could be overwritten by a fast wave at t+1). Overwrite at t+2
//         is ordered behind local finalize-t via the packet-poll chain:
//         my red overwrite t+2 <= my poll t+2 <= producer finalize t+1 <=
//         producer red-barrier t+1 <= producer polled MY finalize-t packets,
//         stored only after my red reads. One __syncthreads per step remains.
//     (d) finalize distributed over waves 0-1 (128 threads, 1 output each).
//     Skew<=1 on hbuf parity carries over (same chain). Stale tag in a slot is
//     t-3 or 0xFFFFFFFF -> exact-equality check never false-positives.
//     VGPR ~110, LDS 16KB -> all 256 blocks co-resident -> spins can't deadlock.

#define RNN_B 64
#define RNN_T 1024
#define RNN_D 512
#define RNN_F 512

// ---------------------------------------------------------------------------
// Kernel 1: x_proj = X @ W_ih + bias.  M=65536, N=512, K=512.  (unchanged)
// ---------------------------------------------------------------------------
__global__ __launch_bounds__(256) void xproj_gemm(
    const float* __restrict__ A,     // [65536, 512]
    const float* __restrict__ W,     // [512, 512]
    const float* __restrict__ bias,  // [512]
    float* __restrict__ C)           // [65536, 512]
{
    __shared__ float As[16][132];
    __shared__ float Bs[16][132];

    const int tid = threadIdx.x;
    const int bid = blockIdx.x;
    const int mt = bid >> 2;
    const int nt = bid & 3;
    const size_t M0 = (size_t)mt * 128;
    const int N0 = nt * 128;

    const int tm = tid >> 4;
    const int tn = tid & 15;

    const int ar = tid >> 2;
    const int ac = (tid & 3) * 4;
    const int br = tid >> 5;
    const int bc = (tid & 31) * 4;

    float acc[8][8];
    #pragma unroll
    for (int i = 0; i < 8; ++i)
        #pragma unroll
        for (int jx = 0; jx < 8; ++jx) acc[i][jx] = 0.f;

    float bv[8];
    #pragma unroll
    for (int i = 0; i < 8; ++i) bv[i] = bias[N0 + tn * 8 + i];

    for (int k0 = 0; k0 < 512; k0 += 16) {
        float4 a0 = *(const float4*)(A + (M0 + ar) * 512 + k0 + ac);
        float4 a1 = *(const float4*)(A + (M0 + ar + 64) * 512 + k0 + ac);
        float4 b0 = *(const float4*)(W + (size_t)(k0 + br) * 512 + N0 + bc);
        float4 b1 = *(const float4*)(W + (size_t)(k0 + br + 8) * 512 + N0 + bc);
        __syncthreads();
        As[ac + 0][ar] = a0.x; As[ac + 1][ar] = a0.y;
        As[ac + 2][ar] = a0.z; As[ac + 3][ar] = a0.w;
        As[ac + 0][ar + 64] = a1.x; As[ac + 1][ar + 64] = a1.y;
        As[ac + 2][ar + 64] = a1.z; As[ac + 3][ar + 64] = a1.w;
        *(float4*)&Bs[br][bc]     = b0;
        *(float4*)&Bs[br + 8][bc] = b1;
        __syncthreads();
        #pragma unroll
        for (int kk = 0; kk < 16; ++kk) {
            float a[8], bb[8];
            *(float4*)&a[0]  = *(const float4*)&As[kk][tm * 8];
            *(float4*)&a[4]  = *(const float4*)&As[kk][tm * 8 + 4];
            *(float4*)&bb[0] = *(const float4*)&Bs[kk][tn * 8];
            *(float4*)&bb[4] = *(const float4*)&Bs[kk][tn * 8 + 4];
            #pragma unroll
            for (int i = 0; i < 8; ++i)
                #pragma unroll
                for (int jx = 0; jx < 8; ++jx)
                    acc[i][jx] = fmaf(a[i], bb[jx], acc[i][jx]);
        }
    }

    #pragma unroll
    for (int i = 0; i < 8; ++i) {
        float* crow = C + (M0 + tm * 8 + i) * 512 + N0 + tn * 8;
        float4 o0, o1;
        o0.x = acc[i][0] + bv[0]; o0.y = acc[i][1] + bv[1];
        o0.z = acc[i][2] + bv[2]; o0.w = acc[i][3] + bv[3];
        o1.x = acc[i][4] + bv[4]; o1.y = acc[i][5] + bv[5];
        o1.z = acc[i][6] + bv[6]; o1.w = acc[i][7] + bv[7];
        *(float4*)crow = o0;
        *((float4*)crow + 1) = o1;
    }
}

// ---------------------------------------------------------------------------
// Kernel 2: the scan.
// ---------------------------------------------------------------------------
__global__ __launch_bounds__(256, 1) void rnn_scan(
    const float* __restrict__ whh,          // [512, 512]
    float* __restrict__ out,                // [64,1024,512]; xp, overwritten with h
    unsigned long long* __restrict__ hbuf)  // [2][64][512] 8B {val,tag} packets
{
    __shared__ float hs[4][512];        // h_{t-1}, partitioned per half-wave (8 KB)
    __shared__ float red[2][8][4][32];  // partials, parity double-buffered (8 KB)

    const int tid = threadIdx.x;
    const int b = blockIdx.x;
    const int r = b & 15;            // row group 0..15 -> batch rows 4r..4r+3
    const int s = b >> 4;            // col slice 0..15 -> cols 32s..32s+31
    const int j = tid & 31;
    const int kq = tid >> 5;         // 0..7 (half-wave id)
    const int kbase = kq * 64;
    const int col = s * 32 + j;      // FMA output column
    const int row0 = r * 4;
    const int colp = kbase + 2 * j;  // cols this lane polls & stages (own k-slice)

    // One-time: weight slice into registers. 64 floats/thread.
    float wreg[64];
    #pragma unroll
    for (int kk = 0; kk < 64; ++kk)
        wreg[kk] = whh[(size_t)(kbase + kk) * RNN_F + col];

    const int orow = kq & 3;         // finalize row for tid<128 (waves 0-1)

    #pragma unroll 1
    for (int t = 0; t < RNN_T; ++t) {
        if (t > 0) {
            // Poll the 8 self-validating packets of MY k-slice (4 rows x col
            // pair colp,colp+1). Whole wave proceeds when its 64 lanes pass ->
            // waits on only this wave's 4 producer blocks.
            const unsigned long long* src = hbuf +
                (size_t)((t + 1) & 1) * (RNN_B * RNN_F) +
                (size_t)row0 * RNN_F + colp;
            const unsigned tagw = (unsigned)(t - 1);
            unsigned long long e0a, e0b, e1a, e1b, e2a, e2b, e3a, e3b;
            for (;;) {
                e0a = __hip_atomic_load(src + 0 * RNN_F + 0, __ATOMIC_RELAXED, __HIP_MEMORY_SCOPE_AGENT);
                e0b = __hip_atomic_load(src + 0 * RNN_F + 1, __ATOMIC_RELAXED, __HIP_MEMORY_SCOPE_AGENT);
                e1a = __hip_atomic_load(src + 1 * RNN_F + 0, __ATOMIC_RELAXED, __HIP_MEMORY_SCOPE_AGENT);
                e1b = __hip_atomic_load(src + 1 * RNN_F + 1, __ATOMIC_RELAXED, __HIP_MEMORY_SCOPE_AGENT);
                e2a = __hip_atomic_load(src + 2 * RNN_F + 0, __ATOMIC_RELAXED, __HIP_MEMORY_SCOPE_AGENT);
                e2b = __hip_atomic_load(src + 2 * RNN_F + 1, __ATOMIC_RELAXED, __HIP_MEMORY_SCOPE_AGENT);
                e3a = __hip_atomic_load(src + 3 * RNN_F + 0, __ATOMIC_RELAXED, __HIP_MEMORY_SCOPE_AGENT);
                e3b = __hip_atomic_load(src + 3 * RNN_F + 1, __ATOMIC_RELAXED, __HIP_MEMORY_SCOPE_AGENT);
                unsigned bad = ((unsigned)(e0a >> 32) ^ tagw) | ((unsigned)(e0b >> 32) ^ tagw)
                             | ((unsigned)(e1a >> 32) ^ tagw) | ((unsigned)(e1b >> 32) ^ tagw)
                             | ((unsigned)(e2a >> 32) ^ tagw) | ((unsigned)(e2b >> 32) ^ tagw)
                             | ((unsigned)(e3a >> 32) ^ tagw) | ((unsigned)(e3b >> 32) ^ tagw);
                if (bad == 0u) break;
                __builtin_amdgcn_s_sleep(1);
            }
            // Stage into MY half-wave's hs slice. Intra-wave lockstep + DS
            // in-order per wave + compiler lgkmcnt make this barrier-free:
            // the only readers are lanes of this same half-wave.
            *(unsigned long long*)&hs[0][colp] = (e0a & 0xFFFFFFFFull) | (e0b << 32);
            *(unsigned long long*)&hs[1][colp] = (e1a & 0xFFFFFFFFull) | (e1b << 32);
            *(unsigned long long*)&hs[2][colp] = (e2a & 0xFFFFFFFFull) | (e2b << 32);
            *(unsigned long long*)&hs[3][colp] = (e3a & 0xFFFFFFFFull) | (e3b << 32);
        }

        // xp load AFTER the poll (so the poll's vmcnt(0) never waits on it);
        // consumed in finalize after FMA+barrier -> HBM latency hidden.
        float xpv = 0.f;
        if (tid < 128)
            xpv = out[((size_t)(row0 + orow) * RNN_T + t) * RNN_F + col];

        float acc0 = 0.f, acc1 = 0.f, acc2 = 0.f, acc3 = 0.f;
        if (t > 0) {
            #pragma unroll
            for (int kk = 0; kk < 64; kk += 4) {
                float4 h0 = *(const float4*)&hs[0][kbase + kk];
                float4 h1 = *(const float4*)&hs[1][kbase + kk];
                float4 h2 = *(const float4*)&hs[2][kbase + kk];
                float4 h3 = *(const float4*)&hs[3][kbase + kk];
                acc0 = fmaf(h0.x, wreg[kk+0], acc0);
                acc0 = fmaf(h0.y, wreg[kk+1], acc0);
                acc0 = fmaf(h0.z, wreg[kk+2], acc0);
                acc0 = fmaf(h0.w, wreg[kk+3], acc0);
                acc1 = fmaf(h1.x, wreg[kk+0], acc1);
                acc1 = fmaf(h1.y, wreg[kk+1], acc1);
                acc1 = fmaf(h1.z, wreg[kk+2], acc1);
                acc1 = fmaf(h1.w, wreg[kk+3], acc1);
                acc2 = fmaf(h2.x, wreg[kk+0], acc2);
                acc2 = fmaf(h2.y, wreg[kk+1], acc2);
                acc2 = fmaf(h2.z, wreg[kk+2], acc2);
                acc2 = fmaf(h2.w, wreg[kk+3], acc2);
                acc3 = fmaf(h3.x, wreg[kk+0], acc3);
                acc3 = fmaf(h3.y, wreg[kk+1], acc3);
                acc3 = fmaf(h3.z, wreg[kk+2], acc3);
                acc3 = fmaf(h3.w, wreg[kk+3], acc3);
            }
        }
        const int par = t & 1;
        red[par][kq][0][j] = acc0;
        red[par][kq][1][j] = acc1;
        red[par][kq][2][j] = acc2;
        red[par][kq][3][j] = acc3;
        __syncthreads();   // the ONE barrier per step (gates red reads & reuse)

        // Finalize: waves 0-1, one output each. Fire-and-forget packet store
        // (issued before the out store; both drained by the next poll's vmcnt).
        if (tid < 128) {
            float sum = 0.f;
            #pragma unroll
            for (int q = 0; q < 8; ++q) sum += red[par][q][orow][j];
            float v = tanhf(xpv + sum);
            unsigned long long* hb = hbuf + (size_t)par * (RNN_B * RNN_F);
            __hip_atomic_store(hb + (size_t)(row0 + orow) * RNN_F + col,
                               ((unsigned long long)(unsigned)t << 32) | __float_as_uint(v),
                               __ATOMIC_RELAXED, __HIP_MEMORY_SCOPE_AGENT);
            out[((size_t)(row0 + orow) * RNN_T + t) * RNN_F + col] = v;
        }
        // Waves 2-3 fall straight through to the next step's poll; red reuse
        // at t+1 targets the other parity, reuse at t+2 is ordered behind this
        // finalize via the packet-poll chain (see header).
    }
}

extern "C" void kernel_launch(void* const* d_in, const int* in_sizes, int n_in,
                              void* d_out, int out_size, void* d_ws, size_t ws_size,
                              hipStream_t stream) {
    const float* X    = (const float*)d_in[0];  // [64,1024,512]
    const float* Wih  = (const float*)d_in[1];  // [512,512]
    const float* Whh  = (const float*)d_in[2];  // [512,512]
    const float* bias = (const float*)d_in[3];  // [512]
    float* out = (float*)d_out;                 // [64,1024,512]

    unsigned long long* hbuf = (unsigned long long*)d_ws;  // 2*64*512*8B = 512 KB

    // Tag field of every packet -> 0xFFFFFFFF (matches no step).
    hipMemsetAsync(hbuf, 0xFF, (size_t)2 * RNN_B * RNN_F * sizeof(unsigned long long),
                   stream);

    xproj_gemm<<<dim3(2048), dim3(256), 0, stream>>>(X, Wih, bias, out);
    rnn_scan<<<dim3(256), dim3(256), 0, stream>>>(Whh, out, hbuf);
}